// Round 9
// baseline (527.436 us; speedup 1.0000x reference)
//
#include <hip/hip_runtime.h>
#include <hip/hip_cooperative_groups.h>
#include <math.h>

namespace cg = cooperative_groups;

constexpr int B  = 128;
constexpr int R  = 4096;
constexpr int IC = 8;
constexpr int C  = 10;
constexpr int O  = 16;
constexpr int CO = C * O;          // 160

constexpr int RCH    = 32;         // r's per chunk
constexpr int NCHUNK = R / RCH;    // 128
constexpr int NBLK   = 256;        // 1 block per CU (cooperative co-residency)
constexpr int WCHUNK = RCH * C * O * IC;   // 40960 floats of W per chunk

using f16x8 = __attribute__((ext_vector_type(8))) _Float16;
using f16x4 = __attribute__((ext_vector_type(4))) _Float16;
using f32x4 = __attribute__((ext_vector_type(4))) float;

// ---- MFMA routing pass over one (chunk, b-half). ----
// Wave = 16 b's; lane: ln = b-col, kb = k-block (only kb==0 carries real k,
// B rows 8..31 are zero so A-garbage there is annihilated).
// D layout: col=b (ln), row=o (kb*4+reg). sacc accumulates in registers.
template<int IT>
__device__ __forceinline__ void pass_body(
    int chunk, int bhalf, int tid,
    const _Float16* __restrict__ W16, const _Float16* __restrict__ xT16,
    const float* __restrict__ vsum, float* __restrict__ s_part)
{
    const int wv = tid >> 6;
    const int l  = tid & 63;
    const int ln = l & 15;
    const int kb = l >> 4;
    const int b  = bhalf * 64 + wv * 16 + ln;
    const int r0 = chunk * RCH;

    float vreg[C][4];                 // v[b][c][o = kb*4 + j]
    if constexpr (IT >= 1) {
        #pragma unroll
        for (int c = 0; c < C; ++c)
            *reinterpret_cast<float4*>(vreg[c]) =
                *reinterpret_cast<const float4*>(vsum + (size_t)b * CO + c * O + kb * 4);
    }

    f32x4 sacc[C];
    #pragma unroll
    for (int c = 0; c < C; ++c) sacc[c] = (f32x4){0.f, 0.f, 0.f, 0.f};

    const _Float16* xptr = xT16 + ((size_t)r0 * B + b) * IC;
    const _Float16* wptr = W16 + ((size_t)r0 * C * O + ln) * IC;

    for (int rr = 0; rr < RCH; ++rr) {
        f16x8 bf;
        #pragma unroll
        for (int j = 0; j < 8; ++j) bf[j] = (_Float16)0.f;
        if (kb == 0) bf = *reinterpret_cast<const f16x8*>(xptr);
        xptr += (size_t)B * IC;

        f32x4 uh[C];
        #pragma unroll
        for (int c = 0; c < C; ++c) {
            f16x8 af = *reinterpret_cast<const f16x8*>(wptr + (size_t)c * (O * IC));
            if constexpr (IT == 0) {
                sacc[c] = __builtin_amdgcn_mfma_f32_16x16x32_f16(af, bf, sacc[c], 0, 0, 0);
            } else {
                uh[c] = __builtin_amdgcn_mfma_f32_16x16x32_f16(
                            af, bf, (f32x4){0.f, 0.f, 0.f, 0.f}, 0, 0, 0);
            }
        }
        wptr += C * O * IC;

        if constexpr (IT >= 1) {
            // logits a[b,c] = sum_o uh*v: 4 in-lane FMA + xor16 + xor32
            float a[C];
            #pragma unroll
            for (int c = 0; c < C; ++c) {
                float p = uh[c][0] * vreg[c][0];
                p = fmaf(uh[c][1], vreg[c][1], p);
                p = fmaf(uh[c][2], vreg[c][2], p);
                p = fmaf(uh[c][3], vreg[c][3], p);
                p += __int_as_float(__builtin_amdgcn_ds_swizzle(__float_as_int(p), 0x401F));
                p += __shfl_xor(p, 32, 64);
                a[c] = p;
            }
            // softmax over c (logits small: no max-subtract), rcp divide
            float sum = 0.f;
            #pragma unroll
            for (int c = 0; c < C; ++c) { a[c] = __expf(a[c]); sum += a[c]; }
            const float inv = __builtin_amdgcn_rcpf(sum);
            #pragma unroll
            for (int c = 0; c < C; ++c) {
                const float wgt = a[c] * inv;
                #pragma unroll
                for (int j = 0; j < 4; ++j)
                    sacc[c][j] = fmaf(wgt, uh[c][j], sacc[c][j]);
            }
        }
    }

    const float scale = (IT == 0) ? 0.1f : 1.0f;    // softmax(0) weight
    float* sp = s_part + ((size_t)chunk * B + b) * CO + kb * 4;
    #pragma unroll
    for (int c = 0; c < C; ++c)
        *reinterpret_cast<float4*>(sp + c * O) =
            make_float4(sacc[c][0] * scale, sacc[c][1] * scale,
                        sacc[c][2] * scale, sacc[c][3] * scale);
}

// ---- reduce + squash for one (b, co-half). 240 threads x 3 chunk-segments. ----
__device__ __forceinline__ void reduce_body(
    int g, int tid, const float* __restrict__ s_part, const float* __restrict__ bias,
    const float* __restrict__ vin, float* __restrict__ vout_v,
    float* __restrict__ vout_sum, float* __restrict__ sh)
{
    const int b    = g & 127;
    const int half = g >> 7;

    if (tid < 240) {
        const int col = tid % 80, seg = tid / 80;
        const int c0 = (seg == 0) ? 0 : (seg == 1 ? 43 : 86);
        const int c1 = (seg == 0) ? 43 : (seg == 1 ? 86 : 128);
        const int co = half * 80 + col;
        float acc = 0.f;
        for (int ch = c0; ch < c1; ++ch)
            acc += s_part[((size_t)ch * B + b) * CO + co];
        sh[seg * 80 + col] = acc;
    }
    __syncthreads();
    if (tid < 80) {
        float s = sh[tid] + sh[80 + tid] + sh[160 + tid] + bias[half * 80 + tid];
        sh[256 + tid] = s;
    }
    __syncthreads();
    if (tid < 80) {
        const int cl = tid >> 4;          // local c (0..4)
        float n = 0.f;
        #pragma unroll
        for (int oo = 0; oo < O; ++oo) { float z = sh[256 + cl * O + oo]; n += z * z; }
        const float s = sh[256 + tid];
        const float v = s * sqrtf(n) / (1.f + n);          // squash
        const size_t idx = (size_t)b * CO + half * 80 + tid;
        if (vout_v)   vout_v[idx] = v;
        if (vout_sum) vout_sum[idx] = (vin ? vin[idx] : 0.f) + v;
    }
    __syncthreads();   // sh reused by later phases
}

// ---- the whole op: converts + 3 routing iterations, one cooperative launch ----
__global__ void __launch_bounds__(256, 1)
digitcaps_all(const float* __restrict__ x, const float* __restrict__ W,
              const float* __restrict__ bias, float* __restrict__ out,
              float* __restrict__ s_part, float* __restrict__ vsumA,
              float* __restrict__ vsumB, _Float16* __restrict__ W16,
              _Float16* __restrict__ xT16)
{
    cg::grid_group grid = cg::this_grid();
    __shared__ float sh[2304];
    const int tid = threadIdx.x;
    const int g   = blockIdx.x;
    // XCD-major decode: XCD k owns chunks [16k,16k+16); both b-half blocks of
    // a chunk land on the same XCD (dispatch round-robins g%8).
    const int xcd   = g & 7;
    const int mid   = (g >> 3) & 15;
    const int bhalf = g >> 7;
    const int chunk = xcd * 16 + mid;      // 0..127

    // ---- phase A: convert W->fp16 (own chunk slice) + transpose x->fp16 ----
    {
        const size_t wbase = (size_t)chunk * WCHUNK + (size_t)bhalf * (WCHUNK / 2);
        const float* wsrc = W + wbase;
        _Float16* wdst = W16 + wbase;
        #pragma unroll
        for (int k = 0; k < 20; ++k) {     // 20480 floats / 256 thr / 4
            const size_t idx = (size_t)(k * 256 + tid) * 4;
            float4 v = *reinterpret_cast<const float4*>(wsrc + idx);
            f16x4 h = {(_Float16)v.x, (_Float16)v.y, (_Float16)v.z, (_Float16)v.w};
            *reinterpret_cast<f16x4*>(wdst + idx) = h;
        }
        const int rt = chunk * RCH + bhalf * 16;   // this block's 16-r tile
        for (int bt = 0; bt < 8; ++bt) {
            const int b0 = bt * 16;
            __syncthreads();
            {
                const int rj = tid & 15, bi = tid >> 4;   // coalesced read over r
                const float* src = x + ((size_t)(b0 + bi) * R + (rt + rj)) * IC;
                float4 a0 = *reinterpret_cast<const float4*>(src);
                float4 a1 = *reinterpret_cast<const float4*>(src + 4);
                float* t = &sh[(bi * 16 + rj) * 9];
                t[0]=a0.x; t[1]=a0.y; t[2]=a0.z; t[3]=a0.w;
                t[4]=a1.x; t[5]=a1.y; t[6]=a1.z; t[7]=a1.w;
            }
            __syncthreads();
            {
                const int bi = tid & 15, rj = tid >> 4;   // coalesced write over b
                const float* t = &sh[(bi * 16 + rj) * 9];
                f16x8 h;
                #pragma unroll
                for (int i = 0; i < IC; ++i) h[i] = (_Float16)t[i];
                *reinterpret_cast<f16x8*>(
                    xT16 + ((size_t)(rt + rj) * B + (b0 + bi)) * IC) = h;
            }
        }
    }
    __threadfence();
    grid.sync();

    // ---- iter 0: uniform weights 0.1 (pure chained MFMA) ----
    pass_body<0>(chunk, bhalf, tid, W16, xT16, nullptr, s_part);
    __threadfence();
    grid.sync();
    reduce_body(g, tid, s_part, bias, nullptr, nullptr, vsumA, sh);   // vsumA = v0
    __threadfence();
    grid.sync();

    // ---- iter 1: logits = uh . v0 ----
    pass_body<1>(chunk, bhalf, tid, W16, xT16, vsumA, s_part);
    __threadfence();
    grid.sync();
    reduce_body(g, tid, s_part, bias, vsumA, nullptr, vsumB, sh);     // vsumB = v0+v1
    __threadfence();
    grid.sync();

    // ---- iter 2: logits = uh . (v0+v1) ----
    pass_body<2>(chunk, bhalf, tid, W16, xT16, vsumB, s_part);
    __threadfence();
    grid.sync();
    reduce_body(g, tid, s_part, bias, nullptr, out, nullptr, sh);     // out = v2
}

extern "C" void kernel_launch(void* const* d_in, const int* in_sizes, int n_in,
                              void* d_out, int out_size, void* d_ws, size_t ws_size,
                              hipStream_t stream)
{
    const float* x    = (const float*)d_in[0];
    const float* W    = (const float*)d_in[1];
    const float* bias = (const float*)d_in[2];
    float* out = (float*)d_out;

    float* ws     = (float*)d_ws;
    float* s_part = ws;                                     // 128*128*160 = 2,621,440 f
    float* vsumA  = s_part + (size_t)NCHUNK * B * CO;       // 20,480 f
    float* vsumB  = vsumA + (size_t)B * CO;                 // 20,480 f
    _Float16* W16  = (_Float16*)(vsumB + (size_t)B * CO);   // 5,242,880 halves (16B-aligned)
    _Float16* xT16 = W16 + (size_t)R * C * O * IC;          // 4,194,304 halves
    // total ~29.5 MB

    void* args[] = {(void*)&x, (void*)&W, (void*)&bias, (void*)&out,
                    (void*)&s_part, (void*)&vsumA, (void*)&vsumB,
                    (void*)&W16, (void*)&xT16};
    hipLaunchCooperativeKernel(reinterpret_cast<void*>(digitcaps_all),
                               dim3(NBLK), dim3(256), args, 0, stream);
}

// Round 10
// 503.547 us; speedup vs baseline: 1.0474x; 1.0474x over previous
//
#include <hip/hip_runtime.h>
#include <math.h>

constexpr int B  = 128;
constexpr int R  = 4096;
constexpr int IC = 8;
constexpr int C  = 10;
constexpr int O  = 16;
constexpr int CO = C * O;        // 160

constexpr int RCH    = 8;        // r's per chunk (small => many chunks => occupancy)
constexpr int NCHUNK = R / RCH;  // 512
constexpr int NWCONV = (R * C * O * IC) / 1024;   // 5120 W-convert blocks
constexpr int NXPOSE = (R / 16) * (B / 16);       // 2048 x-transpose blocks

using f16x8 = __attribute__((ext_vector_type(8))) _Float16;
using f16x4 = __attribute__((ext_vector_type(4))) _Float16;
using f32x4 = __attribute__((ext_vector_type(4))) float;

// DPP add on the VALU pipe. row_ror:N = 0x120|N rotates within each 16-lane row.
template<int CTRL>
__device__ __forceinline__ float dpp_add(float v) {
    return v + __int_as_float(__builtin_amdgcn_update_dpp(
        0, __float_as_int(v), CTRL, 0xF, 0xF, true));
}
__device__ __forceinline__ float rowsum16(float v) {
    v = dpp_add<0x121>(v); v = dpp_add<0x122>(v);
    v = dpp_add<0x124>(v); v = dpp_add<0x128>(v);
    return v;
}

// ---- fused one-time converts: W fp32->fp16 (same layout) + x -> xT16 [r][b][i] ----
__global__ __launch_bounds__(256)
void convert_kernel(const float* __restrict__ x, const float* __restrict__ W,
                    _Float16* __restrict__ W16, _Float16* __restrict__ xT16)
{
    const int bid = blockIdx.x;
    const int tid = threadIdx.x;
    if (bid < NWCONV) {
        const size_t i = ((size_t)bid * 256 + tid) * 4;
        float4 v = *reinterpret_cast<const float4*>(W + i);
        f16x4 h = {(_Float16)v.x, (_Float16)v.y, (_Float16)v.z, (_Float16)v.w};
        *reinterpret_cast<f16x4*>(W16 + i) = h;
    } else {
        __shared__ float tile[16][16][IC + 1];
        const int v  = bid - NWCONV;
        const int r0 = (v & 255) * 16;
        const int b0 = (v >> 8) * 16;
        {
            const int rj = tid & 15, bi = tid >> 4;   // coalesced read over r
            const float* src = x + ((size_t)(b0 + bi) * R + (r0 + rj)) * IC;
            float4 a0 = *reinterpret_cast<const float4*>(src);
            float4 a1 = *reinterpret_cast<const float4*>(src + 4);
            float* t = tile[bi][rj];
            t[0]=a0.x; t[1]=a0.y; t[2]=a0.z; t[3]=a0.w;
            t[4]=a1.x; t[5]=a1.y; t[6]=a1.z; t[7]=a1.w;
        }
        __syncthreads();
        {
            const int bi = tid & 15, rj = tid >> 4;   // coalesced write over b
            const float* t = tile[bi][rj];
            f16x8 h;
            #pragma unroll
            for (int i = 0; i < IC; ++i) h[i] = (_Float16)t[i];
            *reinterpret_cast<f16x8*>(xT16 + ((size_t)(r0 + rj) * B + (b0 + bi)) * IC) = h;
        }
    }
}

// ---- MFMA pass ----
// Grid 1024 = 512 chunks x 2 b-halves, XCD-decoded (XCD k owns chunks
// [64k, 64k+64), both halves on the same XCD -> W slice 1.3 MB L2-resident).
// Wave = 16 b's; lane: ln = b-col, kb = k-block (only kb==0 carries real k;
// B rows 8..31 are zero so A-garbage there is annihilated).
// D layout: col=b (ln), row=o (kb*4+reg). sacc accumulates in registers.
template<int IT>
__global__ __launch_bounds__(256, 4)
void pass_mfma(const _Float16* __restrict__ W16, const _Float16* __restrict__ xT16,
               const float* __restrict__ vsum, float* __restrict__ s_part)
{
    const int tid = threadIdx.x;
    const int wv  = tid >> 6;
    const int l   = tid & 63;
    const int ln  = l & 15;
    const int kb  = l >> 4;

    const int g     = blockIdx.x;
    const int xcd   = g & 7;
    const int t     = g >> 3;          // 0..127
    const int bhalf = t & 1;
    const int cid   = t >> 1;          // 0..63
    const int chunk = xcd * 64 + cid;  // 0..511
    const int b     = bhalf * 64 + wv * 16 + ln;
    const int r0    = chunk * RCH;

    float vreg[C][4];                  // v[b][c][o = kb*4 + j]
    if constexpr (IT >= 1) {
        #pragma unroll
        for (int c = 0; c < C; ++c)
            *reinterpret_cast<float4*>(vreg[c]) =
                *reinterpret_cast<const float4*>(vsum + (size_t)b * CO + c * O + kb * 4);
    }

    f32x4 sacc[C];
    #pragma unroll
    for (int c = 0; c < C; ++c) sacc[c] = (f32x4){0.f, 0.f, 0.f, 0.f};

    const _Float16* xptr = xT16 + ((size_t)r0 * B + b) * IC;
    const _Float16* wptr = W16 + ((size_t)r0 * C * O + ln) * IC;

    #pragma unroll
    for (int rr = 0; rr < RCH; ++rr) {
        f16x8 bf;
        #pragma unroll
        for (int j = 0; j < 8; ++j) bf[j] = (_Float16)0.f;
        if (kb == 0) bf = *reinterpret_cast<const f16x8*>(xptr);
        xptr += (size_t)B * IC;

        f32x4 uh[C];
        #pragma unroll
        for (int c = 0; c < C; ++c) {
            f16x8 af = *reinterpret_cast<const f16x8*>(wptr + (size_t)c * (O * IC));
            if constexpr (IT == 0) {
                sacc[c] = __builtin_amdgcn_mfma_f32_16x16x32_f16(af, bf, sacc[c], 0, 0, 0);
            } else {
                uh[c] = __builtin_amdgcn_mfma_f32_16x16x32_f16(
                            af, bf, (f32x4){0.f, 0.f, 0.f, 0.f}, 0, 0, 0);
            }
        }
        wptr += C * O * IC;

        if constexpr (IT >= 1) {
            // logits a[b,c] = sum_o uh*v: 4 in-lane FMA + xor16 + xor32
            float a[C];
            #pragma unroll
            for (int c = 0; c < C; ++c) {
                float p = uh[c][0] * vreg[c][0];
                p = fmaf(uh[c][1], vreg[c][1], p);
                p = fmaf(uh[c][2], vreg[c][2], p);
                p = fmaf(uh[c][3], vreg[c][3], p);
                p += __int_as_float(__builtin_amdgcn_ds_swizzle(__float_as_int(p), 0x401F));
                p += __shfl_xor(p, 32, 64);
                a[c] = p;
            }
            // softmax over c (logits small: no max-subtract), rcp divide
            float sum = 0.f;
            #pragma unroll
            for (int c = 0; c < C; ++c) { a[c] = __expf(a[c]); sum += a[c]; }
            const float inv = __builtin_amdgcn_rcpf(sum);
            #pragma unroll
            for (int c = 0; c < C; ++c) {
                const float wgt = a[c] * inv;
                #pragma unroll
                for (int j = 0; j < 4; ++j)
                    sacc[c][j] = fmaf(wgt, uh[c][j], sacc[c][j]);
            }
        }
    }

    constexpr float scale = (IT == 0) ? 0.1f : 1.0f;   // softmax(0) weight
    float* sp = s_part + ((size_t)chunk * B + b) * CO + kb * 4;
    #pragma unroll
    for (int c = 0; c < C; ++c)
        *reinterpret_cast<float4*>(sp + c * O) =
            make_float4(sacc[c][0] * scale, sacc[c][1] * scale,
                        sacc[c][2] * scale, sacc[c][3] * scale);
}

// Sum partials over chunks, add bias, squash. Block = one (b, c).
__global__ __launch_bounds__(256)
void reduce_squash(const float* __restrict__ s_part, const float* __restrict__ bias,
                   const float* __restrict__ vin_sum,
                   float* __restrict__ v_out, float* __restrict__ vsum_out)
{
    const int b = blockIdx.x;
    const int c = blockIdx.y;
    const int t = threadIdx.x;
    const int o = t & 15;
    const int q = t >> 4;            // 16 segments of NCHUNK/16 chunks

    float acc = 0.f;
    for (int k = 0; k < NCHUNK / 16; ++k) {
        const int blk = q * (NCHUNK / 16) + k;
        acc += s_part[((size_t)blk * B + b) * CO + c * O + o];
    }
    __shared__ float red[16][O];
    red[q][o] = acc;
    __syncthreads();

    if (t < O) {
        float s = bias[c * O + o];
        #pragma unroll
        for (int k = 0; k < 16; ++k) s += red[k][o];
        float n = rowsum16(s * s);                     // ||s||^2 over o
        float v = s * sqrtf(n) / (1.f + n);            // squash
        const size_t idx = (size_t)b * CO + c * O + o;
        if (v_out)    v_out[idx] = v;
        if (vsum_out) vsum_out[idx] = (vin_sum ? vin_sum[idx] : 0.f) + v;
    }
}

extern "C" void kernel_launch(void* const* d_in, const int* in_sizes, int n_in,
                              void* d_out, int out_size, void* d_ws, size_t ws_size,
                              hipStream_t stream)
{
    const float* x    = (const float*)d_in[0];
    const float* W    = (const float*)d_in[1];
    const float* bias = (const float*)d_in[2];
    float* out = (float*)d_out;

    float* ws     = (float*)d_ws;
    float* s_part = ws;                                     // 512*128*160 = 10,485,760 f (42 MB)
    float* vsumA  = s_part + (size_t)NCHUNK * B * CO;       // 20,480 f
    float* vsumB  = vsumA + (size_t)B * CO;                 // 20,480 f
    _Float16* W16  = (_Float16*)(vsumB + (size_t)B * CO);   // 5,242,880 halves
    _Float16* xT16 = W16 + (size_t)R * C * O * IC;          // 4,194,304 halves
    // total ~61 MB (ws is ~256 MB per the harness's 268 MB poison fill)

    convert_kernel<<<NWCONV + NXPOSE, 256, 0, stream>>>(x, W, W16, xT16);

    dim3 pg(NCHUNK * 2);     // 1024 blocks = 4 per CU, XCD-decoded in-kernel
    dim3 rg(B, C);

    // iter 0: weights uniform 0.1 — pure chained MFMA accumulation
    pass_mfma<0><<<pg, 256, 0, stream>>>(W16, xT16, nullptr, s_part);
    reduce_squash<<<rg, 256, 0, stream>>>(s_part, bias, nullptr, nullptr, vsumA);  // vsumA = v0
    // iter 1: logits = uh . v0
    pass_mfma<1><<<pg, 256, 0, stream>>>(W16, xT16, vsumA, s_part);
    reduce_squash<<<rg, 256, 0, stream>>>(s_part, bias, vsumA, nullptr, vsumB);    // vsumB = v0+v1
    // iter 2: logits = uh . (v0+v1)
    pass_mfma<2><<<pg, 256, 0, stream>>>(W16, xT16, vsumB, s_part);
    reduce_squash<<<rg, 256, 0, stream>>>(s_part, bias, nullptr, out, nullptr);    // out = v2
}

// Round 11
// 134.599 us; speedup vs baseline: 3.9186x; 3.7411x over previous
//
#include <hip/hip_runtime.h>
#include <math.h>

constexpr int B  = 128;
constexpr int R  = 4096;
constexpr int IC = 8;
constexpr int C  = 10;
constexpr int O  = 16;
constexpr int CO = C * O;        // 160

constexpr int RCH    = 8;        // r's per chunk (many chunks => 4096 waves => TLP)
constexpr int NCHUNK = R / RCH;  // 512
constexpr int NWCONV = (R * C * O * IC) / 1024;   // 5120 W-convert blocks
constexpr int NXPOSE = (R / 16) * (B / 16);       // 2048 x-transpose blocks

using f16x8 = __attribute__((ext_vector_type(8))) _Float16;
using f16x4 = __attribute__((ext_vector_type(4))) _Float16;
using f32x4 = __attribute__((ext_vector_type(4))) float;

// DPP add on the VALU pipe. row_ror:N = 0x120|N rotates within each 16-lane row.
template<int CTRL>
__device__ __forceinline__ float dpp_add(float v) {
    return v + __int_as_float(__builtin_amdgcn_update_dpp(
        0, __float_as_int(v), CTRL, 0xF, 0xF, true));
}
__device__ __forceinline__ float rowsum16(float v) {
    v = dpp_add<0x121>(v); v = dpp_add<0x122>(v);
    v = dpp_add<0x124>(v); v = dpp_add<0x128>(v);
    return v;
}

// ---- fused one-time converts: W fp32->fp16 (same layout) + x -> xT16 [r][b][i] ----
__global__ __launch_bounds__(256)
void convert_kernel(const float* __restrict__ x, const float* __restrict__ W,
                    _Float16* __restrict__ W16, _Float16* __restrict__ xT16)
{
    const int bid = blockIdx.x;
    const int tid = threadIdx.x;
    if (bid < NWCONV) {
        const size_t i = ((size_t)bid * 256 + tid) * 4;
        float4 v = *reinterpret_cast<const float4*>(W + i);
        f16x4 h = {(_Float16)v.x, (_Float16)v.y, (_Float16)v.z, (_Float16)v.w};
        *reinterpret_cast<f16x4*>(W16 + i) = h;
    } else {
        __shared__ float tile[16][16][IC + 1];
        const int v  = bid - NWCONV;
        const int r0 = (v & 255) * 16;
        const int b0 = (v >> 8) * 16;
        {
            const int rj = tid & 15, bi = tid >> 4;   // coalesced read over r
            const float* src = x + ((size_t)(b0 + bi) * R + (r0 + rj)) * IC;
            float4 a0 = *reinterpret_cast<const float4*>(src);
            float4 a1 = *reinterpret_cast<const float4*>(src + 4);
            float* t = tile[bi][rj];
            t[0]=a0.x; t[1]=a0.y; t[2]=a0.z; t[3]=a0.w;
            t[4]=a1.x; t[5]=a1.y; t[6]=a1.z; t[7]=a1.w;
        }
        __syncthreads();
        {
            const int bi = tid & 15, rj = tid >> 4;   // coalesced write over b
            const float* t = tile[bi][rj];
            f16x8 h;
            #pragma unroll
            for (int i = 0; i < IC; ++i) h[i] = (_Float16)t[i];
            *reinterpret_cast<f16x8*>(xT16 + ((size_t)(r0 + rj) * B + (b0 + bi)) * IC) = h;
        }
    }
}

// ---- MFMA pass ----
// Grid 1024 = 512 chunks x 2 b-halves, XCD-decoded. Wave = 16 b's; lane:
// ln = b-col, kb = k-block (only kb==0 carries real k; B rows 8..31 zero).
// D layout: col=b (ln), row=o (kb*4+reg). sacc accumulates in registers.
// rr loop MUST stay rolled (#pragma unroll 1): full unroll hoists 80 A-frags
// -> 320 VGPRs -> spill (R10: 459 MB scratch writes, 5x regression).
// launch_bounds(256,3): VGPR cap ~170 fits the ~150-reg natural footprint.
template<int IT>
__global__ __launch_bounds__(256, 3)
void pass_mfma(const _Float16* __restrict__ W16, const _Float16* __restrict__ xT16,
               const float* __restrict__ vsum, float* __restrict__ s_part)
{
    const int tid = threadIdx.x;
    const int wv  = tid >> 6;
    const int l   = tid & 63;
    const int ln  = l & 15;
    const int kb  = l >> 4;

    const int g     = blockIdx.x;
    const int xcd   = g & 7;
    const int t     = g >> 3;          // 0..127
    const int bhalf = t & 1;
    const int cid   = t >> 1;          // 0..63
    const int chunk = xcd * 64 + cid;  // 0..511
    const int b     = bhalf * 64 + wv * 16 + ln;
    const int r0    = chunk * RCH;

    float vreg[C][4];                  // v[b][c][o = kb*4 + j]
    if constexpr (IT >= 1) {
        #pragma unroll
        for (int c = 0; c < C; ++c)
            *reinterpret_cast<float4*>(vreg[c]) =
                *reinterpret_cast<const float4*>(vsum + (size_t)b * CO + c * O + kb * 4);
    }

    f32x4 sacc[C];
    #pragma unroll
    for (int c = 0; c < C; ++c) sacc[c] = (f32x4){0.f, 0.f, 0.f, 0.f};

    const _Float16* xptr = xT16 + ((size_t)r0 * B + b) * IC;
    const _Float16* wptr = W16 + ((size_t)r0 * C * O + ln) * IC;

    #pragma unroll 1
    for (int rr = 0; rr < RCH; ++rr) {
        f16x8 bf;
        #pragma unroll
        for (int j = 0; j < 8; ++j) bf[j] = (_Float16)0.f;
        if (kb == 0) bf = *reinterpret_cast<const f16x8*>(xptr);
        xptr += (size_t)B * IC;

        f32x4 uh[C];
        #pragma unroll
        for (int c = 0; c < C; ++c) {
            f16x8 af = *reinterpret_cast<const f16x8*>(wptr + (size_t)c * (O * IC));
            if constexpr (IT == 0) {
                sacc[c] = __builtin_amdgcn_mfma_f32_16x16x32_f16(af, bf, sacc[c], 0, 0, 0);
            } else {
                uh[c] = __builtin_amdgcn_mfma_f32_16x16x32_f16(
                            af, bf, (f32x4){0.f, 0.f, 0.f, 0.f}, 0, 0, 0);
            }
        }
        wptr += C * O * IC;

        if constexpr (IT >= 1) {
            // logits a[b,c] = sum_o uh*v: 4 in-lane FMA + xor16 + xor32
            float a[C];
            #pragma unroll
            for (int c = 0; c < C; ++c) {
                float p = uh[c][0] * vreg[c][0];
                p = fmaf(uh[c][1], vreg[c][1], p);
                p = fmaf(uh[c][2], vreg[c][2], p);
                p = fmaf(uh[c][3], vreg[c][3], p);
                p += __int_as_float(__builtin_amdgcn_ds_swizzle(__float_as_int(p), 0x401F));
                p += __shfl_xor(p, 32, 64);
                a[c] = p;
            }
            // softmax over c (logits small: no max-subtract), rcp divide
            float sum = 0.f;
            #pragma unroll
            for (int c = 0; c < C; ++c) { a[c] = __expf(a[c]); sum += a[c]; }
            const float inv = __builtin_amdgcn_rcpf(sum);
            #pragma unroll
            for (int c = 0; c < C; ++c) {
                const float wgt = a[c] * inv;
                #pragma unroll
                for (int j = 0; j < 4; ++j)
                    sacc[c][j] = fmaf(wgt, uh[c][j], sacc[c][j]);
            }
        }
    }

    constexpr float scale = (IT == 0) ? 0.1f : 1.0f;   // softmax(0) weight
    float* sp = s_part + ((size_t)chunk * B + b) * CO + kb * 4;
    #pragma unroll
    for (int c = 0; c < C; ++c)
        *reinterpret_cast<float4*>(sp + c * O) =
            make_float4(sacc[c][0] * scale, sacc[c][1] * scale,
                        sacc[c][2] * scale, sacc[c][3] * scale);
}

// Sum partials over chunks, add bias, squash. Block = one (b, c).
__global__ __launch_bounds__(256)
void reduce_squash(const float* __restrict__ s_part, const float* __restrict__ bias,
                   const float* __restrict__ vin_sum,
                   float* __restrict__ v_out, float* __restrict__ vsum_out)
{
    const int b = blockIdx.x;
    const int c = blockIdx.y;
    const int t = threadIdx.x;
    const int o = t & 15;
    const int q = t >> 4;            // 16 segments of NCHUNK/16 chunks

    float acc = 0.f;
    for (int k = 0; k < NCHUNK / 16; ++k) {
        const int blk = q * (NCHUNK / 16) + k;
        acc += s_part[((size_t)blk * B + b) * CO + c * O + o];
    }
    __shared__ float red[16][O];
    red[q][o] = acc;
    __syncthreads();

    if (t < O) {
        float s = bias[c * O + o];
        #pragma unroll
        for (int k = 0; k < 16; ++k) s += red[k][o];
        float n = rowsum16(s * s);                     // ||s||^2 over o
        float v = s * sqrtf(n) / (1.f + n);            // squash
        const size_t idx = (size_t)b * CO + c * O + o;
        if (v_out)    v_out[idx] = v;
        if (vsum_out) vsum_out[idx] = (vin_sum ? vin_sum[idx] : 0.f) + v;
    }
}

extern "C" void kernel_launch(void* const* d_in, const int* in_sizes, int n_in,
                              void* d_out, int out_size, void* d_ws, size_t ws_size,
                              hipStream_t stream)
{
    const float* x    = (const float*)d_in[0];
    const float* W    = (const float*)d_in[1];
    const float* bias = (const float*)d_in[2];
    float* out = (float*)d_out;

    float* ws     = (float*)d_ws;
    float* s_part = ws;                                     // 512*128*160 = 10,485,760 f (42 MB)
    float* vsumA  = s_part + (size_t)NCHUNK * B * CO;       // 20,480 f
    float* vsumB  = vsumA + (size_t)B * CO;                 // 20,480 f
    _Float16* W16  = (_Float16*)(vsumB + (size_t)B * CO);   // 5,242,880 halves
    _Float16* xT16 = W16 + (size_t)R * C * O * IC;          // 4,194,304 halves
    // total ~61 MB

    convert_kernel<<<NWCONV + NXPOSE, 256, 0, stream>>>(x, W, W16, xT16);

    dim3 pg(NCHUNK * 2);     // 1024 blocks, XCD-decoded in-kernel
    dim3 rg(B, C);

    // iter 0: weights uniform 0.1 — pure chained MFMA accumulation
    pass_mfma<0><<<pg, 256, 0, stream>>>(W16, xT16, nullptr, s_part);
    reduce_squash<<<rg, 256, 0, stream>>>(s_part, bias, nullptr, nullptr, vsumA);  // vsumA = v0
    // iter 1: logits = uh . v0
    pass_mfma<1><<<pg, 256, 0, stream>>>(W16, xT16, vsumA, s_part);
    reduce_squash<<<rg, 256, 0, stream>>>(s_part, bias, vsumA, nullptr, vsumB);    // vsumB = v0+v1
    // iter 2: logits = uh . (v0+v1)
    pass_mfma<2><<<pg, 256, 0, stream>>>(W16, xT16, vsumB, s_part);
    reduce_squash<<<rg, 256, 0, stream>>>(s_part, bias, nullptr, out, nullptr);    // out = v2
}

// Round 12
// 101.161 us; speedup vs baseline: 5.2138x; 1.3305x over previous
//
#include <hip/hip_runtime.h>
#include <math.h>

constexpr int B  = 128;
constexpr int R  = 4096;
constexpr int IC = 8;
constexpr int C  = 10;
constexpr int O  = 16;
constexpr int CO = C * O;        // 160

constexpr int RCH    = 16;       // r's per chunk (R8's proven geometry)
constexpr int NCHUNK = R / RCH;  // 256
constexpr int NWCONV = (R * C * O * IC) / 1024;   // 5120 W-convert blocks
constexpr int NXPOSE = (R / 16) * (B / 16);       // 2048 x-transpose blocks

using f16x8 = __attribute__((ext_vector_type(8))) _Float16;
using f16x4 = __attribute__((ext_vector_type(4))) _Float16;
using f32x4 = __attribute__((ext_vector_type(4))) float;

// DPP add on the VALU pipe. row_ror:N = 0x120|N rotates within each 16-lane row.
template<int CTRL>
__device__ __forceinline__ float dpp_add(float v) {
    return v + __int_as_float(__builtin_amdgcn_update_dpp(
        0, __float_as_int(v), CTRL, 0xF, 0xF, true));
}
__device__ __forceinline__ float rowsum16(float v) {
    v = dpp_add<0x121>(v); v = dpp_add<0x122>(v);
    v = dpp_add<0x124>(v); v = dpp_add<0x128>(v);
    return v;
}

// ---- fused one-time converts: W fp32->fp16 (same layout) + x -> xT16 [r][b][i] ----
__global__ __launch_bounds__(256)
void convert_kernel(const float* __restrict__ x, const float* __restrict__ W,
                    _Float16* __restrict__ W16, _Float16* __restrict__ xT16)
{
    const int bid = blockIdx.x;
    const int tid = threadIdx.x;
    if (bid < NWCONV) {
        const size_t i = ((size_t)bid * 256 + tid) * 4;
        float4 v = *reinterpret_cast<const float4*>(W + i);
        f16x4 h = {(_Float16)v.x, (_Float16)v.y, (_Float16)v.z, (_Float16)v.w};
        *reinterpret_cast<f16x4*>(W16 + i) = h;
    } else {
        __shared__ float tile[16][16][IC + 1];
        const int v  = bid - NWCONV;
        const int r0 = (v & 255) * 16;
        const int b0 = (v >> 8) * 16;
        {
            const int rj = tid & 15, bi = tid >> 4;   // coalesced read over r
            const float* src = x + ((size_t)(b0 + bi) * R + (r0 + rj)) * IC;
            float4 a0 = *reinterpret_cast<const float4*>(src);
            float4 a1 = *reinterpret_cast<const float4*>(src + 4);
            float* t = tile[bi][rj];
            t[0]=a0.x; t[1]=a0.y; t[2]=a0.z; t[3]=a0.w;
            t[4]=a1.x; t[5]=a1.y; t[6]=a1.z; t[7]=a1.w;
        }
        __syncthreads();
        {
            const int bi = tid & 15, rj = tid >> 4;   // coalesced write over b
            const float* t = tile[bi][rj];
            f16x8 h;
            #pragma unroll
            for (int i = 0; i < IC; ++i) h[i] = (_Float16)t[i];
            *reinterpret_cast<f16x8*>(xT16 + ((size_t)(r0 + rj) * B + (b0 + bi)) * IC) = h;
        }
    }
}

// ---- pass 0: K-packed GEMM. Routing weights are uniform 0.1, so the per-r
// u_hat sum collapses: pack 4 r's into MFMA K=32 (k = (rr, i)). Lane (ln,kb):
// A row=o=ln, k-block rr=kb -> W16[r0+kb][c][o][:]; B col=b=ln, k rr=kb ->
// xT16[r0+kb][b][:]. Every lane loads real 16B, zero K-waste. ----
__global__ __launch_bounds__(256, 4)
void pass0_gemm(const _Float16* __restrict__ W16, const _Float16* __restrict__ xT16,
                float* __restrict__ s_part)
{
    const int tid = threadIdx.x;
    const int wv  = tid >> 6;
    const int l   = tid & 63;
    const int ln  = l & 15;
    const int kb  = l >> 4;

    const int g     = blockIdx.x;
    const int xcd   = g & 7;
    const int t     = g >> 3;          // 0..63
    const int bhalf = t & 1;
    const int cid   = t >> 1;          // 0..31
    const int chunk = xcd * 32 + cid;  // 0..255
    const int b     = bhalf * 64 + wv * 16 + ln;
    const int r0    = chunk * RCH;

    f32x4 sacc[C];
    #pragma unroll
    for (int c = 0; c < C; ++c) sacc[c] = (f32x4){0.f, 0.f, 0.f, 0.f};

    const _Float16* xptr = xT16 + ((size_t)(r0 + kb) * B + b) * IC;
    const _Float16* wptr = W16 + ((size_t)(r0 + kb) * C * O + ln) * IC;

    #pragma unroll 2
    for (int rp = 0; rp < RCH / 4; ++rp) {
        const f16x8 bf = *reinterpret_cast<const f16x8*>(xptr);
        xptr += (size_t)4 * B * IC;
        #pragma unroll
        for (int c = 0; c < C; ++c) {
            f16x8 af = *reinterpret_cast<const f16x8*>(wptr + (size_t)c * (O * IC));
            sacc[c] = __builtin_amdgcn_mfma_f32_16x16x32_f16(af, bf, sacc[c], 0, 0, 0);
        }
        wptr += (size_t)4 * C * O * IC;
    }

    float* sp = s_part + ((size_t)chunk * B + b) * CO + kb * 4;
    #pragma unroll
    for (int c = 0; c < C; ++c)
        *reinterpret_cast<float4*>(sp + c * O) =
            make_float4(sacc[c][0] * 0.1f, sacc[c][1] * 0.1f,
                        sacc[c][2] * 0.1f, sacc[c][3] * 0.1f);
}

// ---- routing pass (iters 1,2) ----
// Wave = 16 b's; kb = k-block (only kb==0 carries real k; B rows 8..31 zero).
// D: col=b (ln), row=o (kb*4+reg). unroll 2 restores compiler pipelining
// (R11's unroll 1: 41 us latency-bound; full unroll: R10 spill disaster).
template<int IT>
__global__ __launch_bounds__(256, 3)
void pass_mfma(const _Float16* __restrict__ W16, const _Float16* __restrict__ xT16,
               const float* __restrict__ vsum, float* __restrict__ s_part)
{
    const int tid = threadIdx.x;
    const int wv  = tid >> 6;
    const int l   = tid & 63;
    const int ln  = l & 15;
    const int kb  = l >> 4;

    const int g     = blockIdx.x;
    const int xcd   = g & 7;
    const int t     = g >> 3;          // 0..63
    const int bhalf = t & 1;
    const int cid   = t >> 1;          // 0..31
    const int chunk = xcd * 32 + cid;  // 0..255
    const int b     = bhalf * 64 + wv * 16 + ln;
    const int r0    = chunk * RCH;

    float vreg[C][4];                  // v[b][c][o = kb*4 + j]
    #pragma unroll
    for (int c = 0; c < C; ++c)
        *reinterpret_cast<float4*>(vreg[c]) =
            *reinterpret_cast<const float4*>(vsum + (size_t)b * CO + c * O + kb * 4);

    f32x4 sacc[C];
    #pragma unroll
    for (int c = 0; c < C; ++c) sacc[c] = (f32x4){0.f, 0.f, 0.f, 0.f};

    const _Float16* xptr = xT16 + ((size_t)r0 * B + b) * IC;
    const _Float16* wptr = W16 + ((size_t)r0 * C * O + ln) * IC;

    #pragma unroll 2
    for (int rr = 0; rr < RCH; ++rr) {
        f16x8 bf;
        #pragma unroll
        for (int j = 0; j < 8; ++j) bf[j] = (_Float16)0.f;
        if (kb == 0) bf = *reinterpret_cast<const f16x8*>(xptr);
        xptr += (size_t)B * IC;

        f32x4 uh[C];
        #pragma unroll
        for (int c = 0; c < C; ++c) {
            f16x8 af = *reinterpret_cast<const f16x8*>(wptr + (size_t)c * (O * IC));
            uh[c] = __builtin_amdgcn_mfma_f32_16x16x32_f16(
                        af, bf, (f32x4){0.f, 0.f, 0.f, 0.f}, 0, 0, 0);
        }
        wptr += C * O * IC;

        // logits a[b,c] = sum_o uh*v: 4 in-lane FMA + xor16 + xor32
        float a[C];
        #pragma unroll
        for (int c = 0; c < C; ++c) {
            float p = uh[c][0] * vreg[c][0];
            p = fmaf(uh[c][1], vreg[c][1], p);
            p = fmaf(uh[c][2], vreg[c][2], p);
            p = fmaf(uh[c][3], vreg[c][3], p);
            p += __int_as_float(__builtin_amdgcn_ds_swizzle(__float_as_int(p), 0x401F));
            p += __shfl_xor(p, 32, 64);
            a[c] = p;
        }
        // softmax over c (logits small: no max-subtract), rcp divide
        float sum = 0.f;
        #pragma unroll
        for (int c = 0; c < C; ++c) { a[c] = __expf(a[c]); sum += a[c]; }
        const float inv = __builtin_amdgcn_rcpf(sum);
        #pragma unroll
        for (int c = 0; c < C; ++c) {
            const float wgt = a[c] * inv;
            #pragma unroll
            for (int j = 0; j < 4; ++j)
                sacc[c][j] = fmaf(wgt, uh[c][j], sacc[c][j]);
        }
    }

    float* sp = s_part + ((size_t)chunk * B + b) * CO + kb * 4;
    #pragma unroll
    for (int c = 0; c < C; ++c)
        *reinterpret_cast<float4*>(sp + c * O) =
            make_float4(sacc[c][0], sacc[c][1], sacc[c][2], sacc[c][3]);
}

// Sum partials over chunks, add bias, squash. Block = one (b, c).
__global__ __launch_bounds__(256)
void reduce_squash(const float* __restrict__ s_part, const float* __restrict__ bias,
                   const float* __restrict__ vin_sum,
                   float* __restrict__ v_out, float* __restrict__ vsum_out)
{
    const int b = blockIdx.x;
    const int c = blockIdx.y;
    const int t = threadIdx.x;
    const int o = t & 15;
    const int q = t >> 4;            // 16 segments of NCHUNK/16 chunks

    float acc = 0.f;
    for (int k = 0; k < NCHUNK / 16; ++k) {
        const int blk = q * (NCHUNK / 16) + k;
        acc += s_part[((size_t)blk * B + b) * CO + c * O + o];
    }
    __shared__ float red[16][O];
    red[q][o] = acc;
    __syncthreads();

    if (t < O) {
        float s = bias[c * O + o];
        #pragma unroll
        for (int k = 0; k < 16; ++k) s += red[k][o];
        float n = rowsum16(s * s);                     // ||s||^2 over o
        float v = s * sqrtf(n) / (1.f + n);            // squash
        const size_t idx = (size_t)b * CO + c * O + o;
        if (v_out)    v_out[idx] = v;
        if (vsum_out) vsum_out[idx] = (vin_sum ? vin_sum[idx] : 0.f) + v;
    }
}

extern "C" void kernel_launch(void* const* d_in, const int* in_sizes, int n_in,
                              void* d_out, int out_size, void* d_ws, size_t ws_size,
                              hipStream_t stream)
{
    const float* x    = (const float*)d_in[0];
    const float* W    = (const float*)d_in[1];
    const float* bias = (const float*)d_in[2];
    float* out = (float*)d_out;

    float* ws     = (float*)d_ws;
    float* s_part = ws;                                     // 256*128*160 = 5,242,880 f (21 MB)
    float* vsumA  = s_part + (size_t)NCHUNK * B * CO;       // 20,480 f
    float* vsumB  = vsumA + (size_t)B * CO;                 // 20,480 f
    _Float16* W16  = (_Float16*)(vsumB + (size_t)B * CO);   // 5,242,880 halves
    _Float16* xT16 = W16 + (size_t)R * C * O * IC;          // 4,194,304 halves
    // total ~40 MB

    convert_kernel<<<NWCONV + NXPOSE, 256, 0, stream>>>(x, W, W16, xT16);

    dim3 pg(NCHUNK * 2);     // 512 blocks, XCD-decoded in-kernel
    dim3 rg(B, C);

    // iter 0: uniform 0.1 weights — K-packed pure GEMM
    pass0_gemm<<<pg, 256, 0, stream>>>(W16, xT16, s_part);
    reduce_squash<<<rg, 256, 0, stream>>>(s_part, bias, nullptr, nullptr, vsumA);  // vsumA = v0
    // iter 1: logits = uh . v0
    pass_mfma<1><<<pg, 256, 0, stream>>>(W16, xT16, vsumA, s_part);
    reduce_squash<<<rg, 256, 0, stream>>>(s_part, bias, vsumA, nullptr, vsumB);    // vsumB = v0+v1
    // iter 2: logits = uh . (v0+v1)
    pass_mfma<2><<<pg, 256, 0, stream>>>(W16, xT16, vsumB, s_part);
    reduce_squash<<<rg, 256, 0, stream>>>(s_part, bias, nullptr, out, nullptr);    // out = v2
}